// Round 15
// baseline (839.808 us; speedup 1.0000x reference)
//
#include <hip/hip_runtime.h>
#include <math.h>

#define L_ 8
#define D_ 128
#define B_ 8192
#define P_ 28
#define ALPHA_ 0.1f

typedef __attribute__((ext_vector_type(8))) short bf16x8;
typedef __attribute__((ext_vector_type(4))) float f32x4;
union BF8 { int4 i; bf16x8 h; short s[8]; };

__device__ __forceinline__ short f2bf(float f) {
    unsigned u = __float_as_uint(f);
    unsigned r = (u + 0x7fffu + ((u >> 16) & 1u)) >> 16;   // RNE
    return (short)(r & 0xffffu);
}
__device__ __forceinline__ unsigned rne2(float a, float b) {
    unsigned ua = __float_as_uint(a); ua += 0x7fffu + ((ua >> 16) & 1u);
    unsigned ub = __float_as_uint(b); ub += 0x7fffu + ((ub >> 16) & 1u);
    return __builtin_amdgcn_perm(ub, ua, 0x07060302);      // {b_hi16, a_hi16} -> mem order a,b
}
__device__ __forceinline__ unsigned cvt_pk_bf16(float lo, float hi) {
    unsigned r;
    asm("v_cvt_pk_bf16_f32 %0, %1, %2" : "=v"(r) : "v"(lo), "v"(hi));
    return r;
}
__device__ __forceinline__ float fast_tanh(float x) {
    float e = exp2f(x * 2.885390081777927f);               // e^{2x}
    return 1.f - 2.f * __builtin_amdgcn_rcpf(e + 1.f);
}

// ---------------------------------------------------------------------------
// W transpose -> bf16 fragment layout for DIRECT per-wave global A-frag reads.
// Per (p,ch) 64KB: byte offset kb*8192 + ct*1024 + m*64 + q*16, holding W^T
// element (k=kb*32+q*8+e, hidden=ch*128+ct*16+m).
// ---------------------------------------------------------------------------
__global__ void transpose_w(const float* __restrict__ W1, const float* __restrict__ W2,
                            short* __restrict__ T1, short* __restrict__ T2) {
    const float* W = blockIdx.y ? W2 : W1;
    short* T = blockIdx.y ? T2 : T1;
    const int p = blockIdx.x >> 3, kb = blockIdx.x & 7;
    __shared__ float tile[32][260];
    const int tid = threadIdx.x;
    for (int s = tid; s < 8192; s += 256) {
        int kk = s >> 8, n = s & 255;
        tile[kk][n] = W[((size_t)p * 256 + kb * 32 + kk) * 256 + n];
    }
    __syncthreads();
    const int n = tid;
    const int ch = n >> 7, ct = (n >> 4) & 7, mm = n & 15;
    const size_t sb = (((size_t)p * 2 + ch) * 64 + kb * 8) * 512;   // kb-slice base (shorts)
    short tmp[32];
#pragma unroll
    for (int kk = 0; kk < 32; ++kk) tmp[kk] = f2bf(tile[kk][n]);
#pragma unroll
    for (int c4 = 0; c4 < 4; ++c4) {
        BF8 u;
#pragma unroll
        for (int e = 0; e < 8; ++e) u.s[e] = tmp[c4 * 8 + e];
        const int byt = ct * 1024 + mm * 64 + c4 * 16;              // linear
        *(int4*)&T[sb + (byt >> 1)] = u.i;
    }
}

// ---------------------------------------------------------------------------
// S (f32) -> bf16 B-fragment layout, computed ONCE; also initializes
// OUT = 0.9^7 * S (the closed-form propagation base -- finalize is gone).
// ---------------------------------------------------------------------------
__global__ void prep_s16(const float* __restrict__ S, short* __restrict__ S16,
                         float* __restrict__ OUT) {
    __shared__ __align__(16) short ls[8192];            // 16 KB bounce, bank-swizzled
    const int t = threadIdx.x;
    const size_t base = (size_t)blockIdx.x * 8192;      // 64 rows x 128
#pragma unroll
    for (int rr = 0; rr < 8; ++rr) {
        const int idx = rr * 1024 + t * 4;
        const float4 v = *(const float4*)&S[base + idx];
        *(float4*)&OUT[base + idx] = (float4){0.4782969f * v.x, 0.4782969f * v.y,
                                              0.4782969f * v.z, 0.4782969f * v.w};
        const int row = idx >> 7, col = idx & 127;
        const int rgl = row >> 4, mr = row & 15, kq = col >> 3, c4 = (col >> 2) & 1;
        const unsigned w0 = rne2(v.x, v.y), w1 = rne2(v.z, v.w);
        const int byt = (rgl * 4096 + kq * 256 + mr * 16 + c4 * 8) ^ ((kq & 7) << 4);
        *(uint2*)((char*)ls + byt) = (uint2){w0, w1};
    }
    __syncthreads();
#pragma unroll
    for (int r = 0; r < 4; ++r) {
        const int un = r * 256 + t;                      // 16-B unit
        const int kq = (un >> 4) & 15;
        const int byt = (un * 16) ^ ((kq & 7) << 4);
        *(int4*)&S16[base + (size_t)un * 8] = *(const int4*)((const char*)ls + byt);
    }
}

// ---------------------------------------------------------------------------
// Pair-parallel GEMM, single phase, block = (pair p, 64 rows).
// vs round 13/14: round-13 tile restored (r14's retile raised regs 128->140
// and dropped occupancy 34.6->25.9% -> slower); grid swap kept (FETCH
// 48.5->37.9 MB). NEW: the sequential propagation has a closed form with
// per-pair weights -- for pair (i,j), layer i's touch index is j-1 and layer
// j's is i, so OUT = 0.9^7 S + sum over pairs of {0.1*0.9^(7-j) * e[:,:128]
// into layer i, 0.1*0.9^(6-i) * e[:,128:] into layer j}. The epilogue adds
// its weighted e DIRECTLY into OUT via native f32 atomics. This deletes ENT
// (117 MB of round-trip), both finalize dispatches, and the 2-phase split.
// e stays f32 (no bf16 round) -> strictly closer to reference.
// ---------------------------------------------------------------------------
__launch_bounds__(256, 4)
__global__ void pairgemm(const float* __restrict__ ES, const float* __restrict__ b1,
                         const float* __restrict__ b2, const short* __restrict__ S16,
                         const short* __restrict__ T1, const short* __restrict__ T2,
                         float* __restrict__ OUT) {
    __shared__ __align__(16) short Hs[16384];   // 32 KB: 64 rows x 256 hidden, frag layout
    const int rb = blockIdx.x, p = blockIdx.y;
    const int tid = threadIdx.x, lane = tid & 63, w = tid >> 6;
    const int m = lane & 15, q = lane >> 4;
    char* const hsb = (char*)Hs;

    int i = 0, base = 0;
    while (p >= base + (L_ - 1 - i)) { base += L_ - 1 - i; ++i; }
    const int j = i + 1 + (p - base);
    const float es = ES[i * L_ + j];
    const float st = 1.f / (1.f + expf(-es));

    const int rgb = rb * 4;                     // absolute 16-row-group base

    // ============ G1: both hidden halves -> full Hs (one barrier total) =====
    for (int hh = 0; hh < 2; ++hh) {
        const short* wA = T1 + ((size_t)(p * 2 + hh) << 15) + (w * 2) * 512 + m * 32 + q * 8;
        f32x4 acc1[2][4];
#pragma unroll
        for (int at = 0; at < 2; ++at) {
            const f32x4 bv = *(const f32x4*)&b1[p * 256 + hh * 128 + (w * 2 + at) * 16 + q * 4];
#pragma unroll
            for (int nt = 0; nt < 4; ++nt) acc1[at][nt] = bv;
        }
#pragma unroll
        for (int kb = 0; kb < 8; ++kb) {
            const int l = (kb < 4) ? i : j;     // comb = [s_i | s_j]
            const int kbl = kb & 3;
            const bf16x8 A0 = *(const bf16x8*)(wA + kb * 4096);
            const bf16x8 A1 = *(const bf16x8*)(wA + kb * 4096 + 512);
            const short* sp = S16 + ((size_t)l * 512 + rgb) * 2048 + ((kbl * 4 + q) * 16 + m) * 8;
#pragma unroll
            for (int nt = 0; nt < 4; ++nt) {
                const bf16x8 Bf = *(const bf16x8*)(sp + nt * 2048);
                acc1[0][nt] = __builtin_amdgcn_mfma_f32_16x16x32_bf16(A0, Bf, acc1[0][nt], 0, 0, 0);
                acc1[1][nt] = __builtin_amdgcn_mfma_f32_16x16x32_bf16(A1, Bf, acc1[1][nt], 0, 0, 0);
            }
        }
        // tanh -> bf16 -> Hs fragment layout (conflict-free 8B stores)
#pragma unroll
        for (int at = 0; at < 2; ++at) {
            const int cb = (hh * 16 + w * 4 + at * 2 + (q >> 1)) * 256 + m * 16 + (q & 1) * 8;
#pragma unroll
            for (int nt = 0; nt < 4; ++nt) {
                const float v0 = fast_tanh(acc1[at][nt][0]);
                const float v1 = fast_tanh(acc1[at][nt][1]);
                const float v2 = fast_tanh(acc1[at][nt][2]);
                const float v3 = fast_tanh(acc1[at][nt][3]);
                const unsigned p0 = cvt_pk_bf16(v0, v1);
                const unsigned p1 = cvt_pk_bf16(v2, v3);
                *(uint2*)(hsb + nt * 8192 + cb) = (uint2){p0, p1};
            }
        }
    }
    __syncthreads();                            // full H visible

    // ============ G2: full K=256, wave w owns cols [w*64, w*64+64) ==========
    f32x4 acc2[4][4];
#pragma unroll
    for (int ai = 0; ai < 4; ++ai)
#pragma unroll
        for (int nt = 0; nt < 4; ++nt) acc2[ai][nt] = (f32x4){0.f, 0.f, 0.f, 0.f};

#pragma unroll
    for (int kb = 0; kb < 8; ++kb) {
        bf16x8 Hf[4];
#pragma unroll
        for (int nt = 0; nt < 4; ++nt)
            Hf[nt] = *(const bf16x8*)(hsb + nt * 8192 + (kb * 4 + q) * 256 + m * 16);
#pragma unroll
        for (int ai = 0; ai < 4; ++ai) {
            const int ctg = w * 4 + ai;
            const bf16x8 A = *(const bf16x8*)(T2 + ((size_t)(p * 2 + (ctg >> 3)) << 15)
                                              + kb * 4096 + (ctg & 7) * 512 + m * 32 + q * 8);
#pragma unroll
            for (int nt = 0; nt < 4; ++nt)
                acc2[ai][nt] = __builtin_amdgcn_mfma_f32_16x16x32_bf16(A, Hf[nt], acc2[ai][nt], 0, 0, 0);
        }
    }

    // epilogue: weighted atomic scatter into OUT.
    // side-i (cols 0..127): weight 0.1*0.9^(7-j); side-j: 0.1*0.9^(6-i).
    float wi = 0.1f, wj = 0.1f;
    for (int t = 0; t < 7 - j; ++t) wi *= 0.9f;
    for (int t = 0; t < 6 - i; ++t) wj *= 0.9f;
#pragma unroll
    for (int ai = 0; ai < 4; ++ai) {
        const int ctg = w * 4 + ai;
        const int side = ctg >> 3;
        const int l = side ? j : i;
        const float wgt = side ? wj : wi;
        const f32x4 bv = *(const f32x4*)&b2[p * 256 + ctg * 16 + q * 4];
        float* op = OUT + ((size_t)l * B_ + rb * 64 + m) * D_ + (ctg & 7) * 16 + q * 4;
#pragma unroll
        for (int nt = 0; nt < 4; ++nt) {
            float* orow = op + (size_t)(nt * 16) * D_;
#pragma unroll
            for (int r = 0; r < 4; ++r)
                unsafeAtomicAdd(&orow[r], wgt * (st * (acc2[ai][nt][r] + bv[r])));
        }
    }
}

// measures analytically constant (lam1 == 1 after normalize):
// (127+127-255)*1e-12*(-ln 1e-12) = -2.7631021115928547e-11
__global__ void fill_meas(float* __restrict__ M) {
    int t = blockIdx.x * 256 + threadIdx.x;
    if (t < P_ * B_) M[t] = -2.7631021115928547e-11f;
}

extern "C" void kernel_launch(void* const* d_in, const int* in_sizes, int n_in,
                              void* d_out, int out_size, void* d_ws, size_t ws_size,
                              hipStream_t stream) {
    const float* S  = (const float*)d_in[0];
    const float* ES = (const float*)d_in[1];
    const float* W1 = (const float*)d_in[2];
    const float* b1 = (const float*)d_in[3];
    const float* W2 = (const float*)d_in[4];
    const float* b2 = (const float*)d_in[5];

    short* S16 = (short*)d_ws;                           // 16.78 MB
    short* T1  = S16 + (size_t)L_ * B_ * D_;             // 3.67 MB
    short* T2  = T1 + (size_t)P_ * 2 * 32768;            // 3.67 MB (total 24.1 MB)

    float* OUT  = (float*)d_out;                         // updated [L,B,D]
    float* MEAS = OUT + (size_t)L_ * B_ * D_;            // measures [P,B]

    transpose_w<<<dim3(P_ * 8, 2), 256, 0, stream>>>(W1, W2, T1, T2);
    prep_s16<<<dim3(1024), 256, 0, stream>>>(S, S16, OUT);
    pairgemm<<<dim3(128, P_), 256, 0, stream>>>(ES, b1, b2, S16, T1, T2, OUT);
    fill_meas<<<dim3(896), 256, 0, stream>>>(MEAS);
}

// Round 16
// 263.210 us; speedup vs baseline: 3.1906x; 3.1906x over previous
//
#include <hip/hip_runtime.h>
#include <math.h>

#define L_ 8
#define D_ 128
#define B_ 8192
#define P_ 28
#define ALPHA_ 0.1f

typedef __attribute__((ext_vector_type(8))) short bf16x8;
typedef __attribute__((ext_vector_type(4))) float f32x4;
union BF8 { int4 i; bf16x8 h; short s[8]; };

__device__ __forceinline__ short f2bf(float f) {
    unsigned u = __float_as_uint(f);
    unsigned r = (u + 0x7fffu + ((u >> 16) & 1u)) >> 16;   // RNE
    return (short)(r & 0xffffu);
}
__device__ __forceinline__ float bf2f(unsigned short s) {
    return __uint_as_float(((unsigned)s) << 16);
}
__device__ __forceinline__ unsigned rne2(float a, float b) {
    unsigned ua = __float_as_uint(a); ua += 0x7fffu + ((ua >> 16) & 1u);
    unsigned ub = __float_as_uint(b); ub += 0x7fffu + ((ub >> 16) & 1u);
    return __builtin_amdgcn_perm(ub, ua, 0x07060302);      // {b_hi16, a_hi16} -> mem order a,b
}
__device__ __forceinline__ unsigned cvt_pk_bf16(float lo, float hi) {
    unsigned r;
    asm("v_cvt_pk_bf16_f32 %0, %1, %2" : "=v"(r) : "v"(lo), "v"(hi));
    return r;
}
__device__ __forceinline__ float fast_tanh(float x) {
    float e = exp2f(x * 2.885390081777927f);               // e^{2x}
    return 1.f - 2.f * __builtin_amdgcn_rcpf(e + 1.f);
}

// ---------------------------------------------------------------------------
// W transpose -> bf16 fragment layout for DIRECT per-wave global A-frag reads.
// Per (p,ch) 64KB: byte offset kb*8192 + ct*1024 + m*64 + q*16, holding W^T
// element (k=kb*32+q*8+e, hidden=ch*128+ct*16+m).
// ---------------------------------------------------------------------------
__global__ void transpose_w(const float* __restrict__ W1, const float* __restrict__ W2,
                            short* __restrict__ T1, short* __restrict__ T2) {
    const float* W = blockIdx.y ? W2 : W1;
    short* T = blockIdx.y ? T2 : T1;
    const int p = blockIdx.x >> 3, kb = blockIdx.x & 7;
    __shared__ float tile[32][260];
    const int tid = threadIdx.x;
    for (int s = tid; s < 8192; s += 256) {
        int kk = s >> 8, n = s & 255;
        tile[kk][n] = W[((size_t)p * 256 + kb * 32 + kk) * 256 + n];
    }
    __syncthreads();
    const int n = tid;
    const int ch = n >> 7, ct = (n >> 4) & 7, mm = n & 15;
    const size_t sb = (((size_t)p * 2 + ch) * 64 + kb * 8) * 512;   // kb-slice base (shorts)
    short tmp[32];
#pragma unroll
    for (int kk = 0; kk < 32; ++kk) tmp[kk] = f2bf(tile[kk][n]);
#pragma unroll
    for (int c4 = 0; c4 < 4; ++c4) {
        BF8 u;
#pragma unroll
        for (int e = 0; e < 8; ++e) u.s[e] = tmp[c4 * 8 + e];
        const int byt = ct * 1024 + mm * 64 + c4 * 16;              // linear
        *(int4*)&T[sb + (byt >> 1)] = u.i;
    }
}

// ---------------------------------------------------------------------------
// S (f32) -> bf16 B-fragment layout, computed ONCE. Per 16-row group rg:
// 2048 shorts, elem(row,k) at (k/8 *16 + row%16)*8 + k%8.
// ---------------------------------------------------------------------------
__global__ void prep_s16(const float* __restrict__ S, short* __restrict__ S16) {
    __shared__ __align__(16) short ls[8192];            // 16 KB bounce, bank-swizzled
    const int t = threadIdx.x;
    const size_t base = (size_t)blockIdx.x * 8192;      // 64 rows x 128
#pragma unroll
    for (int rr = 0; rr < 8; ++rr) {
        const int idx = rr * 1024 + t * 4;
        const float4 v = *(const float4*)&S[base + idx];
        const int row = idx >> 7, col = idx & 127;
        const int rgl = row >> 4, mr = row & 15, kq = col >> 3, c4 = (col >> 2) & 1;
        const unsigned w0 = rne2(v.x, v.y), w1 = rne2(v.z, v.w);
        const int byt = (rgl * 4096 + kq * 256 + mr * 16 + c4 * 8) ^ ((kq & 7) << 4);
        *(uint2*)((char*)ls + byt) = (uint2){w0, w1};
    }
    __syncthreads();
#pragma unroll
    for (int r = 0; r < 4; ++r) {
        const int un = r * 256 + t;                      // 16-B unit
        const int kq = (un >> 4) & 15;
        const int byt = (un * 16) ^ ((kq & 7) << 4);
        *(int4*)&S16[base + (size_t)un * 8] = *(const int4*)((const char*)ls + byt);
    }
}

// ---------------------------------------------------------------------------
// Pair-parallel GEMM: the round-13 kernel (best measured: 73.5 us/phase,
// 267 total) with EXACTLY ONE change: grid x=rb, y=p (round-14's swap,
// un-confounded from its bad retile). Co-resident blocks share one pair's
// 128 KB W instead of churning all 7.3 MB through the 4 MB per-XCD L2
// (r13 FETCH 48.5 MB -> r14 37.9 MB, the only clean signal from r14).
// Round-15's atomic-scatter epilogue is fully reverted (924 MB of
// memory-side atomic write amplification, 750 us, MfmaUtil 3%).
// ---------------------------------------------------------------------------
__launch_bounds__(256, 4)
__global__ void pairgemm(const float* __restrict__ ES, const float* __restrict__ b1,
                         const float* __restrict__ b2, const short* __restrict__ S16,
                         const short* __restrict__ T1, const short* __restrict__ T2,
                         short* __restrict__ ENT, int b0) {
    __shared__ __align__(16) short Hs[16384];   // 32 KB: 64 rows x 256 hidden, frag layout
    const int rb = blockIdx.x, p = blockIdx.y;
    const int tid = threadIdx.x, lane = tid & 63, w = tid >> 6;
    const int m = lane & 15, q = lane >> 4;
    char* const hsb = (char*)Hs;

    int i = 0, base = 0;
    while (p >= base + (L_ - 1 - i)) { base += L_ - 1 - i; ++i; }
    const int j = i + 1 + (p - base);
    const float es = ES[i * L_ + j];
    const float st = 1.f / (1.f + expf(-es));

    const int rgb = (b0 >> 4) + rb * 4;         // absolute 16-row-group base

    // ============ G1: both hidden halves -> full Hs (one barrier total) =====
    for (int hh = 0; hh < 2; ++hh) {
        const short* wA = T1 + ((size_t)(p * 2 + hh) << 15) + (w * 2) * 512 + m * 32 + q * 8;
        f32x4 acc1[2][4];
#pragma unroll
        for (int at = 0; at < 2; ++at) {
            const f32x4 bv = *(const f32x4*)&b1[p * 256 + hh * 128 + (w * 2 + at) * 16 + q * 4];
#pragma unroll
            for (int nt = 0; nt < 4; ++nt) acc1[at][nt] = bv;
        }
#pragma unroll
        for (int kb = 0; kb < 8; ++kb) {
            const int l = (kb < 4) ? i : j;     // comb = [s_i | s_j]
            const int kbl = kb & 3;
            const bf16x8 A0 = *(const bf16x8*)(wA + kb * 4096);
            const bf16x8 A1 = *(const bf16x8*)(wA + kb * 4096 + 512);
            const short* sp = S16 + ((size_t)l * 512 + rgb) * 2048 + ((kbl * 4 + q) * 16 + m) * 8;
#pragma unroll
            for (int nt = 0; nt < 4; ++nt) {
                const bf16x8 Bf = *(const bf16x8*)(sp + nt * 2048);
                acc1[0][nt] = __builtin_amdgcn_mfma_f32_16x16x32_bf16(A0, Bf, acc1[0][nt], 0, 0, 0);
                acc1[1][nt] = __builtin_amdgcn_mfma_f32_16x16x32_bf16(A1, Bf, acc1[1][nt], 0, 0, 0);
            }
        }
        // tanh -> bf16 -> Hs fragment layout (conflict-free 8B stores)
#pragma unroll
        for (int at = 0; at < 2; ++at) {
            const int cb = (hh * 16 + w * 4 + at * 2 + (q >> 1)) * 256 + m * 16 + (q & 1) * 8;
#pragma unroll
            for (int nt = 0; nt < 4; ++nt) {
                const float v0 = fast_tanh(acc1[at][nt][0]);
                const float v1 = fast_tanh(acc1[at][nt][1]);
                const float v2 = fast_tanh(acc1[at][nt][2]);
                const float v3 = fast_tanh(acc1[at][nt][3]);
                const unsigned p0 = cvt_pk_bf16(v0, v1);
                const unsigned p1 = cvt_pk_bf16(v2, v3);
                *(uint2*)(hsb + nt * 8192 + cb) = (uint2){p0, p1};
            }
        }
    }
    __syncthreads();                            // full H visible

    // ============ G2: full K=256, wave w owns cols [w*64, w*64+64) ==========
    f32x4 acc2[4][4];
#pragma unroll
    for (int ai = 0; ai < 4; ++ai)
#pragma unroll
        for (int nt = 0; nt < 4; ++nt) acc2[ai][nt] = (f32x4){0.f, 0.f, 0.f, 0.f};

#pragma unroll
    for (int kb = 0; kb < 8; ++kb) {
        bf16x8 Hf[4];
#pragma unroll
        for (int nt = 0; nt < 4; ++nt)
            Hf[nt] = *(const bf16x8*)(hsb + nt * 8192 + (kb * 4 + q) * 256 + m * 16);
#pragma unroll
        for (int ai = 0; ai < 4; ++ai) {
            const int ctg = w * 4 + ai;
            const bf16x8 A = *(const bf16x8*)(T2 + ((size_t)(p * 2 + (ctg >> 3)) << 15)
                                              + kb * 4096 + (ctg & 7) * 512 + m * 32 + q * 8);
#pragma unroll
            for (int nt = 0; nt < 4; ++nt)
                acc2[ai][nt] = __builtin_amdgcn_mfma_f32_16x16x32_bf16(A, Hf[nt], acc2[ai][nt], 0, 0, 0);
        }
    }

    // epilogue: ENT = st*(G2 + b2) -> bf16, row-major [4096][256] per pair
    short* Ep = ENT + (size_t)p * 4096 * 256;
#pragma unroll
    for (int ai = 0; ai < 4; ++ai) {
        const int ctg = w * 4 + ai;
        const f32x4 bv = *(const f32x4*)&b2[p * 256 + ctg * 16 + q * 4];
#pragma unroll
        for (int nt = 0; nt < 4; ++nt) {
            const int row = rb * 64 + nt * 16 + m;
            const float e0 = st * (acc2[ai][nt][0] + bv[0]);
            const float e1 = st * (acc2[ai][nt][1] + bv[1]);
            const float e2 = st * (acc2[ai][nt][2] + bv[2]);
            const float e3 = st * (acc2[ai][nt][3] + bv[3]);
            const unsigned p0 = cvt_pk_bf16(e0, e1);
            const unsigned p1 = cvt_pk_bf16(e2, e3);
            *(uint2*)&Ep[(size_t)row * 256 + ctg * 16 + q * 4] = (uint2){p0, p1};
        }
    }
}

// ---------------------------------------------------------------------------
// finalize: u <- u + alpha*(e - u) over layer k's 7 touching pairs in global
// pair order. Streams ENT (row-major) + S. Also fills this phase's MEAS
// slab (constant) -- absorbs the fill_meas dispatch.
// ---------------------------------------------------------------------------
__global__ void finalize(const float* __restrict__ S, const short* __restrict__ ENT,
                         float* __restrict__ OUT, float* __restrict__ MEAS, int b0) {
    const int idx = blockIdx.x * 256 + threadIdx.x;     // 524288 per phase
    if (idx < P_ * 4096) {                              // MEAS [P][B], this phase's b-range
        const int p = idx >> 12, bl = idx & 4095;
        MEAS[p * B_ + b0 + bl] = -2.7631021115928547e-11f;
    }
    const int k = idx >> 16;
    const int rem = idx & 65535;
    const int rl = rem >> 4;                            // 0..4095 phase-local row
    const int d0 = (rem & 15) * 8;
    const size_t sOff = ((size_t)k * B_ + b0 + rl) * D_ + d0;
    float4 u0 = *(const float4*)&S[sOff];
    float4 u1 = *(const float4*)&S[sOff + 4];
    float u[8] = {u0.x, u0.y, u0.z, u0.w, u1.x, u1.y, u1.z, u1.w};
#pragma unroll
    for (int it = 0; it < 7; ++it) {
        const int mp = it + (it >= k ? 1 : 0);
        const int li = k < mp ? k : mp;
        const int lj = k < mp ? mp : k;
        const int p  = li * 7 - ((li * (li - 1)) >> 1) + (lj - li - 1);
        const int side = (k == li) ? 0 : 1;
        const unsigned short* e = (const unsigned short*)ENT
            + ((size_t)p * 4096 + rl) * 256 + side * 128 + d0;
        ushort4 a = *(const ushort4*)e;
        ushort4 c = *(const ushort4*)(e + 4);
        u[0] += ALPHA_ * (bf2f(a.x) - u[0]);
        u[1] += ALPHA_ * (bf2f(a.y) - u[1]);
        u[2] += ALPHA_ * (bf2f(a.z) - u[2]);
        u[3] += ALPHA_ * (bf2f(a.w) - u[3]);
        u[4] += ALPHA_ * (bf2f(c.x) - u[4]);
        u[5] += ALPHA_ * (bf2f(c.y) - u[5]);
        u[6] += ALPHA_ * (bf2f(c.z) - u[6]);
        u[7] += ALPHA_ * (bf2f(c.w) - u[7]);
    }
    *(float4*)&OUT[sOff]     = (float4){u[0], u[1], u[2], u[3]};
    *(float4*)&OUT[sOff + 4] = (float4){u[4], u[5], u[6], u[7]};
}

extern "C" void kernel_launch(void* const* d_in, const int* in_sizes, int n_in,
                              void* d_out, int out_size, void* d_ws, size_t ws_size,
                              hipStream_t stream) {
    const float* S  = (const float*)d_in[0];
    const float* ES = (const float*)d_in[1];
    const float* W1 = (const float*)d_in[2];
    const float* b1 = (const float*)d_in[3];
    const float* W2 = (const float*)d_in[4];
    const float* b2 = (const float*)d_in[5];

    short* S16 = (short*)d_ws;                           // 16.78 MB
    short* T1  = S16 + (size_t)L_ * B_ * D_;             // 3.67 MB
    short* T2  = T1 + (size_t)P_ * 2 * 32768;            // 3.67 MB
    short* ENT = T2 + (size_t)P_ * 2 * 32768;            // 58.72 MB (total 82.84 MB, proven)

    float* OUT  = (float*)d_out;                         // updated [L,B,D]
    float* MEAS = OUT + (size_t)L_ * B_ * D_;            // measures [P,B]

    transpose_w<<<dim3(P_ * 8, 2), 256, 0, stream>>>(W1, W2, T1, T2);
    prep_s16<<<dim3(1024), 256, 0, stream>>>(S, S16);
    for (int ph = 0; ph < 2; ++ph) {
        const int b0 = ph * 4096;
        pairgemm<<<dim3(64, P_), 256, 0, stream>>>(ES, b1, b2, S16, T1, T2, ENT, b0);
        finalize<<<dim3(2048), 256, 0, stream>>>(S, ENT, OUT, MEAS, b0);
    }
}